// Round 11
// baseline (171.520 us; speedup 1.0000x reference)
//
#include <hip/hip_runtime.h>
#include <hip/hip_bf16.h>
#include <math.h>

#define HH 56
#define WW 56
#define HW 3136
#define NHEAD 4
#define RP 111
#define TP 113                       // padded rpe table dim
#define TPE 12769                    // 113*113
#define SCALE 0.17677669529663687f   // 32^-0.5
#define LOG2E 1.44269504088896f
#define QSC (SCALE * LOG2E)
#define BLEN 224                     // per-block n range (4 h-rows)
#define NSLAB 14

typedef unsigned short ushortT;
typedef __attribute__((ext_vector_type(8))) short short8v;
typedef __attribute__((ext_vector_type(16))) float f32x16;

// ---- ws layout (float offsets) ----
#define OFF_AA   8192u
#define OFF_W4   12288u
#define OFF_KBF  24832u                      // 4*3136*32 ushort, (h,n,c)
#define OFF_VBF  225536u                     // (h,c,n) bf16
#define OFF_QBF  426240u                     // (h,m,c) bf16, SCALE*log2e folded
#define OFF_KWT  1028352u
#define OFF_VWT  1044736u
#define OFF_OWT  1061120u
#define OFF_XT   1077504u                    // 3136 x 128 f32
#define OFF_QT   1478912u                    // 3136 x 128 f32
#define OFF_TP4  1880320u                    // 4*113*113 float4 (log2e-scaled quads)
#define OFF_ATT2 2084672u                    // (hd, m, c) f32 un-normalized, 401408
#define OFF_SUM  (OFF_ATT2 + 401408u)        // (hd, m) f32, 12544
#define ZERO_F4  103504u                     // ceil((401408+12544+64)/4)

__device__ __forceinline__ ushortT f2bf(float f) {
    unsigned u = __float_as_uint(f);
    u += 0x7fffu + ((u >> 16) & 1u);
    return (ushortT)(u >> 16);
}

__device__ __forceinline__ unsigned cvtpk(float lo, float hi) {
    unsigned r;
    asm("v_cvt_pk_bf16_f32 %0, %1, %2" : "=v"(r) : "v"(lo), "v"(hi));
    return r;
}

__device__ __forceinline__ float fexp2(float x) {
    float r;
    asm("v_exp_f32 %0, %1" : "=v"(r) : "v"(x));
    return r;
}

__device__ __forceinline__ float wave_sum(float v) {
#pragma unroll
    for (int o = 1; o < 64; o <<= 1) v += __shfl_xor(v, o);
    return v;
}

// ------------- prep: weights T, quad rpe table, x/q transpose, zero accum --------
__global__ __launch_bounds__(256) void prep_all_kernel(
    const float* __restrict__ kw, const float* __restrict__ vw, const float* __restrict__ ow,
    const float* __restrict__ rpe, const float* __restrict__ x, const float* __restrict__ query,
    float* __restrict__ kwT, float* __restrict__ vwT, float* __restrict__ owT,
    float4* __restrict__ tp4, float* __restrict__ xT, float* __restrict__ qT,
    ushortT* __restrict__ qbf, float* __restrict__ zbase) {
    const int job = blockIdx.y;
    __shared__ float tile[32][33];
    if (job < 3) {
        int i = blockIdx.x * 256 + threadIdx.x;
        if (i >= 16384) return;
        const float* srcw = (job == 0) ? kw : (job == 1) ? vw : ow;
        float* dstw       = (job == 0) ? kwT : (job == 1) ? vwT : owT;
        dstw[(i & 127) * 128 + (i >> 7)] = srcw[i];
    } else if (job == 3) {
        int i = blockIdx.x * 256 + threadIdx.x;
        if (i >= NHEAD * TPE) return;
        int hd = i / TPE, r = i % TPE;
        int py = r / TP, px = r % TP;
        const float* tb = rpe + hd * RP * RP;
        bool ry0 = (py >= 1) && (py <= RP);
        bool ry1 = (py <= RP - 1);               // py+1 in [1,RP]
        bool cx0 = (px >= 1) && (px <= RP);
        bool cx1 = (px <= RP - 1);
        float4 v;
        v.x = (ry0 && cx0) ? tb[(py - 1) * RP + (px - 1)] * LOG2E : 0.f;
        v.y = (ry0 && cx1) ? tb[(py - 1) * RP + px] * LOG2E : 0.f;
        v.z = (ry1 && cx0) ? tb[py * RP + (px - 1)] * LOG2E : 0.f;
        v.w = (ry1 && cx1) ? tb[py * RP + px] * LOG2E : 0.f;
        tp4[i] = v;
    } else if (job == 6) {
        int i = blockIdx.x * 256 + threadIdx.x;
        if (i < ZERO_F4) ((float4*)zbase)[i] = make_float4(0.f, 0.f, 0.f, 0.f);
    } else {
        int bx = blockIdx.x;
        if (bx >= 392) return;
        const float* src = (job == 5) ? query : x;
        float* dst       = (job == 5) ? qT : xT;
        int pt = (bx % 98) * 32, ct = (bx / 98) * 32;
        int jj = threadIdx.x & 31, ii = threadIdx.x >> 5;
#pragma unroll
        for (int r = 0; r < 4; r++)
            tile[ii + r * 8][jj] = src[(ct + ii + r * 8) * HW + pt + jj];
        __syncthreads();
#pragma unroll
        for (int r = 0; r < 4; r++) {
            int p = pt + ii + r * 8, cc = ct + jj;
            float val = tile[jj][ii + r * 8];
            dst[p * 128 + cc] = val;
            if (job == 5)
                qbf[(size_t)((cc >> 5) * HW + p) * 32 + (cc & 31)] = f2bf(val * QSC);
        }
    }
}

// ------- fused: conv-offset (dw3x3+LN+GELU+1x1+tanh) + bilinear sample + k/v proj
__global__ __launch_bounds__(128) void sample_kv_kernel(
    const float* __restrict__ xT, const float* __restrict__ qT,
    const float* __restrict__ dww, const float* __restrict__ dwb,
    const float* __restrict__ lnw, const float* __restrict__ lnb,
    const float* __restrict__ pww,
    const float* __restrict__ kwT, const float* __restrict__ vwT,
    const float* __restrict__ kb, const float* __restrict__ vb,
    ushortT* __restrict__ kbf, ushortT* __restrict__ vbf,
    int* __restrict__ aa, float4* __restrict__ w4g) {
    const int n0 = blockIdx.x * 8;               // 392 blocks; 8|56 so one h-row
    const int tid = threadIdx.x;                 // = channel c
    const int h = n0 / WW, w0 = n0 % WW;
    const int wid = tid >> 6;
    const bool l0 = ((tid & 63) == 0);

    __shared__ float xs[128 * 9];
    __shared__ int   cidx[8][4];
    __shared__ float cw[8][4];
    __shared__ ushortT kst[8][128];
    __shared__ float red_a[2][8], red_b[2][8], red_y[2][8], red_x[2][8];

    float dwwr[9];
#pragma unroll
    for (int k = 0; k < 9; k++) dwwr[k] = dww[tid * 9 + k];
    float qv[3][10];
#pragma unroll
    for (int ky = 0; ky < 3; ky++) {
        int yy = h + ky - 1;
        bool vy = (unsigned)yy < (unsigned)HH;
#pragma unroll
        for (int t = 0; t < 10; t++) {
            int xx = w0 + t - 1;
            bool v = vy && ((unsigned)xx < (unsigned)WW);
            qv[ky][t] = v ? qT[(yy * WW + xx) * 128 + tid] : 0.f;
        }
    }
    float tj[8];
#pragma unroll
    for (int j = 0; j < 8; j++) {
        float t = dwb[tid];
#pragma unroll
        for (int ky = 0; ky < 3; ky++)
#pragma unroll
            for (int kx = 0; kx < 3; kx++)
                t += qv[ky][j + kx] * dwwr[ky * 3 + kx];
        tj[j] = t;
    }
#pragma unroll
    for (int j = 0; j < 8; j++) { float s = wave_sum(tj[j]); if (l0) red_a[wid][j] = s; }
    __syncthreads();
    float dj[8];
#pragma unroll
    for (int j = 0; j < 8; j++) {
        float mu = (red_a[0][j] + red_a[1][j]) * (1.f / 128.f);
        dj[j] = tj[j] - mu;
        float s = wave_sum(dj[j] * dj[j]);
        if (l0) red_b[wid][j] = s;
    }
    __syncthreads();
    float py = pww[tid], px = pww[128 + tid];
#pragma unroll
    for (int j = 0; j < 8; j++) {
        float var = (red_b[0][j] + red_b[1][j]) * (1.f / 128.f);
        float tn = dj[j] / sqrtf(var + 1e-5f) * lnw[tid] + lnb[tid];
        float g = 0.5f * tn * (1.f + erff(tn * 0.70710678118654752f));
        float sy = wave_sum(g * py);
        float sx = wave_sum(g * px);
        if (l0) { red_y[wid][j] = sy; red_x[wid][j] = sx; }
    }
    __syncthreads();

    if (tid < 8) {
        int j = tid;
        float thy = tanhf(red_y[0][j] + red_y[1][j]);
        float thx = tanhf(red_x[0][j] + red_x[1][j]);
        int hh = h, ww2 = w0 + j;
        float gy = thy * (0.5f / 55.f) + ((float)hh * (2.f / 55.f) - 1.f);
        float gx = thx * (0.5f / 55.f) + ((float)ww2 * (2.f / 55.f) - 1.f);
        float fx = (gx + 1.f) * 27.5f;
        float fy = (gy + 1.f) * 27.5f;
        float x0f = floorf(fx), y0f = floorf(fy);
        float wx = fx - x0f, wy = fy - y0f;
        int x0 = (int)x0f, y0 = (int)y0f;
#pragma unroll
        for (int k = 0; k < 4; k++) {
            int xi = x0 + (k & 1), yi = y0 + (k >> 1);
            float wgt = ((k & 1) ? wx : 1.f - wx) * ((k >> 1) ? wy : 1.f - wy);
            bool v = (xi >= 0) && (xi < WW) && (yi >= 0) && (yi < HH);
            cidx[j][k] = min(max(yi, 0), HH - 1) * WW + min(max(xi, 0), WW - 1);
            cw[j][k] = v ? wgt : 0.f;
        }
        float ty = 55.f - (float)hh - 0.25f * thy;
        float tx = 55.f - (float)ww2 - 0.25f * thx;
        float tyf = floorf(ty), txf = floorf(tx);
        float wyb = ty - tyf, wxb = tx - txf;
        aa[n0 + j] = ((int)tyf) * TP + (int)txf + TP + 1;
        float4 wv;
        wv.x = (1.f - wxb) * (1.f - wyb);
        wv.y = wxb * (1.f - wyb);
        wv.z = (1.f - wxb) * wyb;
        wv.w = wxb * wyb;
        w4g[n0 + j] = wv;
    }
    __syncthreads();

#pragma unroll
    for (int j = 0; j < 8; j++) {
        float s = cw[j][0] * xT[cidx[j][0] * 128 + tid]
                + cw[j][1] * xT[cidx[j][1] * 128 + tid]
                + cw[j][2] * xT[cidx[j][2] * 128 + tid]
                + cw[j][3] * xT[cidx[j][3] * 128 + tid];
        xs[tid * 9 + j] = s;
    }
    __syncthreads();

    float ak[8], av[8];
#pragma unroll
    for (int j = 0; j < 8; j++) { ak[j] = 0.f; av[j] = 0.f; }
    for (int c = 0; c < 128; c++) {
        float wk = kwT[c * 128 + tid];
        float wv = vwT[c * 128 + tid];
#pragma unroll
        for (int j = 0; j < 8; j++) {
            float xv = xs[c * 9 + j];
            ak[j] += wk * xv;
            av[j] += wv * xv;
        }
    }
    float kbv = kb[tid], vbv = vb[tid];
    int hh2 = tid >> 5, ch = tid & 31;

    unsigned vp[4];
#pragma unroll
    for (int q = 0; q < 4; q++)
        vp[q] = (unsigned)f2bf(av[2 * q] + vbv) | ((unsigned)f2bf(av[2 * q + 1] + vbv) << 16);
    *(uint4*)(vbf + (size_t)(hh2 * 32 + ch) * HW + n0) = make_uint4(vp[0], vp[1], vp[2], vp[3]);

#pragma unroll
    for (int j = 0; j < 8; j++) kst[j][tid] = f2bf(ak[j] + kbv);
    __syncthreads();
#pragma unroll
    for (int r = 0; r < 4; r++) {
        int lin = tid + 128 * r;
        int j = lin >> 6, dd = lin & 63;
        int o = 2 * dd;
        unsigned val = *(unsigned*)&kst[j][o];
        int hd2 = o >> 5, ch2 = o & 31;
        ((unsigned*)kbf)[((size_t)(hd2 * HW + n0 + j) * 32 + ch2) >> 1] = val;
    }
}

// -------- MFMA flash attention; 64m x 224n blocks; quad-table bias; atomics ------
__device__ __forceinline__ void mkw(float pa0, float pa1, float pb0, float pb1, int h,
                                    unsigned &wlo, unsigned &whi) {
    float ta0 = __shfl_xor(pa0, 32);
    float ta1 = __shfl_xor(pa1, 32);
    float tb0 = __shfl_xor(pb0, 32);
    float tb1 = __shfl_xor(pb1, 32);
    wlo = cvtpk(h ? tb0 : pa0, h ? tb1 : pa1);
    whi = cvtpk(h ? pb0 : ta0, h ? pb1 : ta1);
}

__global__ __launch_bounds__(256) void attn_kernel(
    const ushortT* __restrict__ qbf, const ushortT* __restrict__ kbf,
    const ushortT* __restrict__ vbf,
    const int* __restrict__ aa, const float4* __restrict__ w4,
    const float4* __restrict__ tp4g, float* __restrict__ att2, float* __restrict__ sums) {
    const int bx = blockIdx.x;         // 0..13 (224-n slabs = 4 h-rows)
    const int mtile = blockIdx.y;      // 0..48 (64-m tiles)
    const int hd = blockIdx.z;         // 0..3
    const int tid = threadIdx.x;       // 256
    const int wv = tid >> 6;
    const int msub = wv & 1;
    const int csub = wv >> 1;          // nt parity
    const int l = tid & 63;
    const int lm = l & 31;
    const int h = l >> 5;

    const int N0 = bx * BLEN;
    const int m0 = mtile * 64;
    const int mg = m0 + msub * 32 + lm;

    __shared__ int aa_s[BLEN];
    __shared__ float4 w4_s[BLEN];
    __shared__ float4 tpw[6 * TP];

    // analytic window: aa rows (tyf+1) in [52-h0, 56-h0]; + m rows [rm0, rm0+1]
    const int h0 = bx * 4;
    const int rm0 = m0 / WW;
    const int R0 = 52 - h0 + rm0;
    const int rbase = R0 * TP;

    const float4* srcw = tp4g + (size_t)hd * TPE + rbase;
    for (int i = tid; i < 6 * TP; i += 256) tpw[i] = srcw[i];
    if (tid < BLEN) {
        aa_s[tid] = aa[N0 + tid] - rbase;
        w4_s[tid] = w4[N0 + tid];
    }
    __syncthreads();

    const int base_m = (mg / WW) * TP + (mg % WW);

    const ushortT* qb = qbf + (size_t)(hd * HW + mg) * 32 + h * 8;
    short8v qf0 = *(const short8v*)(qb);
    short8v qf1 = *(const short8v*)(qb + 16);

    f32x16 accO;
#pragma unroll
    for (int i = 0; i < 16; i++) accO[i] = 0.f;
    float ssum = 0.f;

    for (int nt = csub; nt < 7; nt += 2) {
        const ushortT* ka = kbf + (size_t)(hd * HW + N0 + nt * 32 + lm) * 32 + h * 8;
        short8v kf0 = *(const short8v*)(ka);
        short8v kf1 = *(const short8v*)(ka + 16);
        f32x16 s;
#pragma unroll
        for (int i = 0; i < 16; i++) s[i] = 0.f;
        s = __builtin_amdgcn_mfma_f32_32x32x16_bf16(kf0, qf0, s, 0, 0, 0);
        s = __builtin_amdgcn_mfma_f32_32x32x16_bf16(kf1, qf1, s, 0, 0, 0);

        float p[16];
#pragma unroll
        for (int r = 0; r < 16; ++r) {
            int nl = nt * 32 + (r & 3) + 8 * (r >> 2) + 4 * h;
            int a0 = aa_s[nl] + base_m;
            float4 wvv = w4_s[nl];
            float4 t4 = tpw[a0];
            float bias = wvv.x * t4.x + wvv.y * t4.y + wvv.z * t4.z + wvv.w * t4.w;
            float pr = fexp2(s[r] + bias);     // q,table pre-scaled by log2e
            ssum += pr;
            p[r] = pr;
        }

        union { unsigned u[4]; short8v s8; } A0, A1;
        mkw(p[0], p[1], p[4], p[5], h, A0.u[0], A0.u[2]);
        mkw(p[2], p[3], p[6], p[7], h, A0.u[1], A0.u[3]);
        mkw(p[8], p[9], p[12], p[13], h, A1.u[0], A1.u[2]);
        mkw(p[10], p[11], p[14], p[15], h, A1.u[1], A1.u[3]);

        const ushortT* va = vbf + (size_t)(hd * 32 + lm) * HW + N0 + nt * 32 + h * 8;
        short8v vf0 = *(const short8v*)(va);
        short8v vf1 = *(const short8v*)(va + 16);
        accO = __builtin_amdgcn_mfma_f32_32x32x16_bf16(A0.s8, vf0, accO, 0, 0, 0);
        accO = __builtin_amdgcn_mfma_f32_32x32x16_bf16(A1.s8, vf1, accO, 0, 0, 0);
    }

    // atomic merge into att2 (hd, m, c) and sums (hd, m)
    float* abase = att2 + (size_t)(hd * HW + m0 + msub * 32) * 32 + lm;
#pragma unroll
    for (int r = 0; r < 16; ++r) {
        int mr = (r & 3) + 8 * (r >> 2) + 4 * h;
        atomicAdd(abase + (size_t)mr * 32, accO[r]);
    }
    float st = ssum + __shfl_xor(ssum, 32);
    if (h == 0) atomicAdd(&sums[hd * HW + mg], st);
}

// -------- normalize att2 + output 1x1 conv ---------------------------------------
__global__ __launch_bounds__(128) void combine_out_kernel(
    const float* __restrict__ att2, const float* __restrict__ sums,
    const float* __restrict__ owT, const float* __restrict__ ob, float* __restrict__ out) {
    int m0 = blockIdx.x * 8;           // 392 blocks
    int tid = threadIdx.x;             // (hd, c)
    int hd = tid >> 5, c = tid & 31;

    __shared__ float at[128 * 9];
    __shared__ float inv_s[4][8];

    if (tid < 32) {
        int hh = tid >> 3, j = tid & 7;
        inv_s[hh][j] = 1.f / sums[hh * HW + m0 + j];
    }
    __syncthreads();

#pragma unroll
    for (int j = 0; j < 8; j++)
        at[tid * 9 + j] = att2[(size_t)(hd * HW + m0 + j) * 32 + c] * inv_s[hd][j];
    __syncthreads();

    float acc[8];
#pragma unroll
    for (int j = 0; j < 8; j++) acc[j] = 0.f;
    for (int cc = 0; cc < 128; cc++) {
        float w = owT[cc * 128 + tid];
        const float* arow = at + cc * 9;
#pragma unroll
        for (int j = 0; j < 8; j++) acc[j] += w * arow[j];
    }
    float b = ob[tid];
#pragma unroll
    for (int j = 0; j < 8; j++) out[tid * HW + m0 + j] = acc[j] + b;
}

extern "C" void kernel_launch(void* const* d_in, const int* in_sizes, int n_in,
                              void* d_out, int out_size, void* d_ws, size_t ws_size,
                              hipStream_t stream) {
    const float* x     = (const float*)d_in[0];
    const float* query = (const float*)d_in[1];
    const float* dww   = (const float*)d_in[2];
    const float* dwb   = (const float*)d_in[3];
    const float* lnw   = (const float*)d_in[4];
    const float* lnb   = (const float*)d_in[5];
    const float* pww   = (const float*)d_in[6];
    const float* kw    = (const float*)d_in[7];
    const float* kb    = (const float*)d_in[8];
    const float* vw    = (const float*)d_in[9];
    const float* vb    = (const float*)d_in[10];
    const float* ow    = (const float*)d_in[11];
    const float* ob    = (const float*)d_in[12];
    const float* rpe   = (const float*)d_in[13];
    float* out = (float*)d_out;
    float* ws  = (float*)d_ws;

    prep_all_kernel<<<dim3(405, 7), 256, 0, stream>>>(
        kw, vw, ow, rpe, x, query,
        ws + OFF_KWT, ws + OFF_VWT, ws + OFF_OWT, (float4*)(ws + OFF_TP4),
        ws + OFF_XT, ws + OFF_QT, (ushortT*)(ws + OFF_QBF), ws + OFF_ATT2);
    sample_kv_kernel<<<392, 128, 0, stream>>>(
        ws + OFF_XT, ws + OFF_QT, dww, dwb, lnw, lnb, pww,
        ws + OFF_KWT, ws + OFF_VWT, kb, vb,
        (ushortT*)(ws + OFF_KBF), (ushortT*)(ws + OFF_VBF),
        (int*)(ws + OFF_AA), (float4*)(ws + OFF_W4));
    attn_kernel<<<dim3(NSLAB, 49, NHEAD), 256, 0, stream>>>(
        (const ushortT*)(ws + OFF_QBF), (const ushortT*)(ws + OFF_KBF),
        (const ushortT*)(ws + OFF_VBF),
        (const int*)(ws + OFF_AA), (const float4*)(ws + OFF_W4),
        (const float4*)(ws + OFF_TP4), ws + OFF_ATT2, ws + OFF_SUM);
    combine_out_kernel<<<392, 128, 0, stream>>>(ws + OFF_ATT2, ws + OFF_SUM,
                                                ws + OFF_OWT, ob, out);
}

// Round 12
// 158.433 us; speedup vs baseline: 1.0826x; 1.0826x over previous
//
#include <hip/hip_runtime.h>
#include <hip/hip_bf16.h>
#include <math.h>

#define HH 56
#define WW 56
#define HW 3136
#define NHEAD 4
#define RP 111
#define TP 113                       // padded rpe table dim
#define TPE 12769                    // 113*113
#define SCALE 0.17677669529663687f   // 32^-0.5
#define LOG2E 1.44269504088896f
#define QSC (SCALE * LOG2E)
#define CLEN 224                     // per-wave n range
#define BLEN 448                     // per-block n range
#define NSTEP 7                      // 224/32

typedef unsigned short ushortT;
typedef __attribute__((ext_vector_type(8))) short short8v;
typedef __attribute__((ext_vector_type(16))) float f32x16;

// ---- ws layout (float offsets) ----
#define OFF_AA   8192u
#define OFF_W4   12288u
#define OFF_KBF  24832u                      // 4*3136*32 ushort, (h,n,c)
#define OFF_VBF  225536u                     // (h,c,n) bf16
#define OFF_QBF  426240u                     // (h,m,c) bf16, SCALE*log2e folded
#define OFF_KWT  1028352u
#define OFF_VWT  1044736u
#define OFF_OWT  1061120u
#define OFF_XT   1077504u                    // 3136 x 128 f32
#define OFF_QT   1478912u                    // 3136 x 128 f32
#define OFF_TP2  1880320u                    // 4*113*113 float2 (log2e-scaled)
#define OFF_ATT2 1982976u                    // (hd, m, c) f32 un-normalized, 401408
#define OFF_SUM  (OFF_ATT2 + 401408u)        // (hd, m) f32, 12544
#define ZERO_F4  103504u                     // ceil((401408+12544+64)/4)

__device__ __forceinline__ ushortT f2bf(float f) {
    unsigned u = __float_as_uint(f);
    u += 0x7fffu + ((u >> 16) & 1u);
    return (ushortT)(u >> 16);
}

__device__ __forceinline__ unsigned cvtpk(float lo, float hi) {
    unsigned r;
    asm("v_cvt_pk_bf16_f32 %0, %1, %2" : "=v"(r) : "v"(lo), "v"(hi));
    return r;
}

__device__ __forceinline__ float fexp2(float x) {
    float r;
    asm("v_exp_f32 %0, %1" : "=v"(r) : "v"(x));
    return r;
}

__device__ __forceinline__ float wave_sum(float v) {
#pragma unroll
    for (int o = 1; o < 64; o <<= 1) v += __shfl_xor(v, o);
    return v;
}

// ------------- prep: weights T, rpe table, x/q transpose, zero accum -------------
__global__ __launch_bounds__(256) void prep_all_kernel(
    const float* __restrict__ kw, const float* __restrict__ vw, const float* __restrict__ ow,
    const float* __restrict__ rpe, const float* __restrict__ x, const float* __restrict__ query,
    float* __restrict__ kwT, float* __restrict__ vwT, float* __restrict__ owT,
    float2* __restrict__ tp2, float* __restrict__ xT, float* __restrict__ qT,
    ushortT* __restrict__ qbf, float* __restrict__ zbase) {
    const int job = blockIdx.y;
    __shared__ float tile[32][33];
    if (job < 3) {
        int i = blockIdx.x * 256 + threadIdx.x;
        if (i >= 16384) return;
        const float* srcw = (job == 0) ? kw : (job == 1) ? vw : ow;
        float* dstw       = (job == 0) ? kwT : (job == 1) ? vwT : owT;
        dstw[(i & 127) * 128 + (i >> 7)] = srcw[i];
    } else if (job == 3) {
        int i = blockIdx.x * 256 + threadIdx.x;
        if (i >= NHEAD * TPE) return;
        int hd = i / TPE, r = i % TPE;
        int py = r / TP, px = r % TP;
        float v0 = 0.f, v1 = 0.f;
        if (py >= 1 && py <= RP) {
            if (px >= 1 && px <= RP) v0 = rpe[hd * RP * RP + (py - 1) * RP + (px - 1)] * LOG2E;
            if (px <= RP - 1)        v1 = rpe[hd * RP * RP + (py - 1) * RP + px] * LOG2E;
        }
        tp2[i] = make_float2(v0, v1);
    } else if (job == 6) {
        int i = blockIdx.x * 256 + threadIdx.x;
        if (i < ZERO_F4) ((float4*)zbase)[i] = make_float4(0.f, 0.f, 0.f, 0.f);
    } else {
        int bx = blockIdx.x;
        if (bx >= 392) return;
        const float* src = (job == 5) ? query : x;
        float* dst       = (job == 5) ? qT : xT;
        int pt = (bx % 98) * 32, ct = (bx / 98) * 32;
        int jj = threadIdx.x & 31, ii = threadIdx.x >> 5;
#pragma unroll
        for (int r = 0; r < 4; r++)
            tile[ii + r * 8][jj] = src[(ct + ii + r * 8) * HW + pt + jj];
        __syncthreads();
#pragma unroll
        for (int r = 0; r < 4; r++) {
            int p = pt + ii + r * 8, cc = ct + jj;
            float val = tile[jj][ii + r * 8];
            dst[p * 128 + cc] = val;
            if (job == 5)
                qbf[(size_t)((cc >> 5) * HW + p) * 32 + (cc & 31)] = f2bf(val * QSC);
        }
    }
}

// ------- fused: conv-offset (dw3x3+LN+GELU+1x1+tanh) + bilinear sample + k/v proj
__global__ __launch_bounds__(128) void sample_kv_kernel(
    const float* __restrict__ xT, const float* __restrict__ qT,
    const float* __restrict__ dww, const float* __restrict__ dwb,
    const float* __restrict__ lnw, const float* __restrict__ lnb,
    const float* __restrict__ pww,
    const float* __restrict__ kwT, const float* __restrict__ vwT,
    const float* __restrict__ kb, const float* __restrict__ vb,
    ushortT* __restrict__ kbf, ushortT* __restrict__ vbf,
    int* __restrict__ aa, float4* __restrict__ w4g) {
    const int n0 = blockIdx.x * 8;               // 392 blocks; 8|56 so one h-row
    const int tid = threadIdx.x;                 // = channel c
    const int h = n0 / WW, w0 = n0 % WW;
    const int wid = tid >> 6;
    const bool l0 = ((tid & 63) == 0);

    __shared__ float xs[128 * 9];
    __shared__ int   cidx[8][4];
    __shared__ float cw[8][4];
    __shared__ ushortT kst[8][128];
    __shared__ float red_a[2][8], red_b[2][8], red_y[2][8], red_x[2][8];

    float dwwr[9];
#pragma unroll
    for (int k = 0; k < 9; k++) dwwr[k] = dww[tid * 9 + k];
    float qv[3][10];
#pragma unroll
    for (int ky = 0; ky < 3; ky++) {
        int yy = h + ky - 1;
        bool vy = (unsigned)yy < (unsigned)HH;
#pragma unroll
        for (int t = 0; t < 10; t++) {
            int xx = w0 + t - 1;
            bool v = vy && ((unsigned)xx < (unsigned)WW);
            qv[ky][t] = v ? qT[(yy * WW + xx) * 128 + tid] : 0.f;
        }
    }
    float tj[8];
#pragma unroll
    for (int j = 0; j < 8; j++) {
        float t = dwb[tid];
#pragma unroll
        for (int ky = 0; ky < 3; ky++)
#pragma unroll
            for (int kx = 0; kx < 3; kx++)
                t += qv[ky][j + kx] * dwwr[ky * 3 + kx];
        tj[j] = t;
    }
#pragma unroll
    for (int j = 0; j < 8; j++) { float s = wave_sum(tj[j]); if (l0) red_a[wid][j] = s; }
    __syncthreads();
    float dj[8];
#pragma unroll
    for (int j = 0; j < 8; j++) {
        float mu = (red_a[0][j] + red_a[1][j]) * (1.f / 128.f);
        dj[j] = tj[j] - mu;
        float s = wave_sum(dj[j] * dj[j]);
        if (l0) red_b[wid][j] = s;
    }
    __syncthreads();
    float py = pww[tid], px = pww[128 + tid];
#pragma unroll
    for (int j = 0; j < 8; j++) {
        float var = (red_b[0][j] + red_b[1][j]) * (1.f / 128.f);
        float tn = dj[j] / sqrtf(var + 1e-5f) * lnw[tid] + lnb[tid];
        float g = 0.5f * tn * (1.f + erff(tn * 0.70710678118654752f));
        float sy = wave_sum(g * py);
        float sx = wave_sum(g * px);
        if (l0) { red_y[wid][j] = sy; red_x[wid][j] = sx; }
    }
    __syncthreads();

    if (tid < 8) {
        int j = tid;
        float thy = tanhf(red_y[0][j] + red_y[1][j]);
        float thx = tanhf(red_x[0][j] + red_x[1][j]);
        int hh = h, ww2 = w0 + j;
        float gy = thy * (0.5f / 55.f) + ((float)hh * (2.f / 55.f) - 1.f);
        float gx = thx * (0.5f / 55.f) + ((float)ww2 * (2.f / 55.f) - 1.f);
        float fx = (gx + 1.f) * 27.5f;
        float fy = (gy + 1.f) * 27.5f;
        float x0f = floorf(fx), y0f = floorf(fy);
        float wx = fx - x0f, wy = fy - y0f;
        int x0 = (int)x0f, y0 = (int)y0f;
#pragma unroll
        for (int k = 0; k < 4; k++) {
            int xi = x0 + (k & 1), yi = y0 + (k >> 1);
            float wgt = ((k & 1) ? wx : 1.f - wx) * ((k >> 1) ? wy : 1.f - wy);
            bool v = (xi >= 0) && (xi < WW) && (yi >= 0) && (yi < HH);
            cidx[j][k] = min(max(yi, 0), HH - 1) * WW + min(max(xi, 0), WW - 1);
            cw[j][k] = v ? wgt : 0.f;
        }
        float ty = 55.f - (float)hh - 0.25f * thy;
        float tx = 55.f - (float)ww2 - 0.25f * thx;
        float tyf = floorf(ty), txf = floorf(tx);
        float wyb = ty - tyf, wxb = tx - txf;
        aa[n0 + j] = ((int)tyf) * TP + (int)txf + TP + 1;
        float4 wv;
        wv.x = (1.f - wxb) * (1.f - wyb);
        wv.y = wxb * (1.f - wyb);
        wv.z = (1.f - wxb) * wyb;
        wv.w = wxb * wyb;
        w4g[n0 + j] = wv;
    }
    __syncthreads();

#pragma unroll
    for (int j = 0; j < 8; j++) {
        float s = cw[j][0] * xT[cidx[j][0] * 128 + tid]
                + cw[j][1] * xT[cidx[j][1] * 128 + tid]
                + cw[j][2] * xT[cidx[j][2] * 128 + tid]
                + cw[j][3] * xT[cidx[j][3] * 128 + tid];
        xs[tid * 9 + j] = s;
    }
    __syncthreads();

    float ak[8], av[8];
#pragma unroll
    for (int j = 0; j < 8; j++) { ak[j] = 0.f; av[j] = 0.f; }
    for (int c = 0; c < 128; c++) {
        float wk = kwT[c * 128 + tid];
        float wv = vwT[c * 128 + tid];
#pragma unroll
        for (int j = 0; j < 8; j++) {
            float xv = xs[c * 9 + j];
            ak[j] += wk * xv;
            av[j] += wv * xv;
        }
    }
    float kbv = kb[tid], vbv = vb[tid];
    int hh2 = tid >> 5, ch = tid & 31;

    unsigned vp[4];
#pragma unroll
    for (int q = 0; q < 4; q++)
        vp[q] = (unsigned)f2bf(av[2 * q] + vbv) | ((unsigned)f2bf(av[2 * q + 1] + vbv) << 16);
    *(uint4*)(vbf + (size_t)(hh2 * 32 + ch) * HW + n0) = make_uint4(vp[0], vp[1], vp[2], vp[3]);

#pragma unroll
    for (int j = 0; j < 8; j++) kst[j][tid] = f2bf(ak[j] + kbv);
    __syncthreads();
#pragma unroll
    for (int r = 0; r < 4; r++) {
        int lin = tid + 128 * r;
        int j = lin >> 6, dd = lin & 63;
        int o = 2 * dd;
        unsigned val = *(unsigned*)&kst[j][o];
        int hd2 = o >> 5, ch2 = o & 31;
        ((unsigned*)kbf)[((size_t)(hd2 * HW + n0 + j) * 32 + ch2) >> 1] = val;
    }
}

// -------- MFMA flash attention; 4-wave blocks (64m x 448n); k/v prefetch ---------
__device__ __forceinline__ void mkw(float pa0, float pa1, float pb0, float pb1, int h,
                                    unsigned &wlo, unsigned &whi) {
    float ta0 = __shfl_xor(pa0, 32);
    float ta1 = __shfl_xor(pa1, 32);
    float tb0 = __shfl_xor(pb0, 32);
    float tb1 = __shfl_xor(pb1, 32);
    wlo = cvtpk(h ? tb0 : pa0, h ? tb1 : pa1);
    whi = cvtpk(h ? pb0 : ta0, h ? pb1 : ta1);
}

__global__ __launch_bounds__(256) void attn_kernel(
    const ushortT* __restrict__ qbf, const ushortT* __restrict__ kbf,
    const ushortT* __restrict__ vbf,
    const int* __restrict__ aa, const float4* __restrict__ w4,
    const float2* __restrict__ tp2g, float* __restrict__ att2, float* __restrict__ sums) {
    const int bx = blockIdx.x;         // 0..6  (448-n slabs)
    const int mtile = blockIdx.y;      // 0..48 (64-m tiles)
    const int hd = blockIdx.z;         // 0..3
    const int tid = threadIdx.x;       // 256
    const int wv = tid >> 6;
    const int msub = wv & 1;
    const int csub = wv >> 1;
    const int l = tid & 63;
    const int lm = l & 31;
    const int h = l >> 5;

    const int N0 = bx * BLEN;
    const int m0 = mtile * 64;
    const int mg = m0 + msub * 32 + lm;

    __shared__ int aa_s[BLEN];
    __shared__ float4 w4_s[BLEN];
    __shared__ float2 tpw[12 * TP];

    // analytic table window (448n slab = 8 full h-rows)
    const int h_min = N0 / WW;
    const int rm0 = m0 / WW, rm1 = (m0 + 63) / WW;
    const int R0 = 48 - h_min + rm0;
    const int NR = 10 + rm1 - rm0;               // <= 12
    const int rbase = R0 * TP;

    const float2* srcw = tp2g + hd * TPE + rbase;
    for (int i = tid; i < NR * TP; i += 256) tpw[i] = srcw[i];
    for (int i = tid; i < BLEN; i += 256) {
        aa_s[i] = aa[N0 + i] - rbase;
        w4_s[i] = w4[N0 + i];
    }
    __syncthreads();

    const int base_m = (mg / WW) * TP + (mg % WW);

    const ushortT* qb = qbf + (size_t)(hd * HW + mg) * 32 + h * 8;
    short8v qf0 = *(const short8v*)(qb);
    short8v qf1 = *(const short8v*)(qb + 16);

    const int nwave = N0 + csub * CLEN;
    const ushortT* kbp = kbf + (size_t)(hd * HW + nwave) * 32;
    const ushortT* vbp = vbf + (size_t)(hd * 32 + lm) * HW + nwave;

    f32x16 accO;
#pragma unroll
    for (int i = 0; i < 16; i++) accO[i] = 0.f;
    float ssum = 0.f;

    // prologue: load tile 0 into registers
    const ushortT* ka0 = kbp + (size_t)(lm) * 32 + h * 8;
    short8v kf0 = *(const short8v*)(ka0);
    short8v kf1 = *(const short8v*)(ka0 + 16);
    const ushortT* va0 = vbp + h * 8;
    short8v vf0 = *(const short8v*)(va0);
    short8v vf1 = *(const short8v*)(va0 + 16);

    for (int nt = 0; nt < NSTEP; ++nt) {
        // issue next tile's loads FIRST (hide L2 latency under this iter's chain)
        int ntn = (nt + 1 < NSTEP) ? nt + 1 : nt;
        const ushortT* kan = kbp + (size_t)(ntn * 32 + lm) * 32 + h * 8;
        short8v nk0 = *(const short8v*)(kan);
        short8v nk1 = *(const short8v*)(kan + 16);
        const ushortT* van = vbp + ntn * 32 + h * 8;
        short8v nv0 = *(const short8v*)(van);
        short8v nv1 = *(const short8v*)(van + 16);

        f32x16 s;
#pragma unroll
        for (int i = 0; i < 16; i++) s[i] = 0.f;
        s = __builtin_amdgcn_mfma_f32_32x32x16_bf16(kf0, qf0, s, 0, 0, 0);
        s = __builtin_amdgcn_mfma_f32_32x32x16_bf16(kf1, qf1, s, 0, 0, 0);

        float p[16];
#pragma unroll
        for (int r = 0; r < 16; ++r) {
            int nl = csub * CLEN + nt * 32 + (r & 3) + 8 * (r >> 2) + 4 * h;
            int a0 = aa_s[nl] + base_m;
            float4 wvv = w4_s[nl];
            float2 t01 = tpw[a0];
            float2 t23 = tpw[a0 + TP];
            float bias = wvv.x * t01.x + wvv.y * t01.y + wvv.z * t23.x + wvv.w * t23.y;
            float pr = fexp2(s[r] + bias);     // q,table pre-scaled by log2e
            ssum += pr;
            p[r] = pr;
        }

        union { unsigned u[4]; short8v s8; } A0, A1;
        mkw(p[0], p[1], p[4], p[5], h, A0.u[0], A0.u[2]);
        mkw(p[2], p[3], p[6], p[7], h, A0.u[1], A0.u[3]);
        mkw(p[8], p[9], p[12], p[13], h, A1.u[0], A1.u[2]);
        mkw(p[10], p[11], p[14], p[15], h, A1.u[1], A1.u[3]);

        accO = __builtin_amdgcn_mfma_f32_32x32x16_bf16(A0.s8, vf0, accO, 0, 0, 0);
        accO = __builtin_amdgcn_mfma_f32_32x32x16_bf16(A1.s8, vf1, accO, 0, 0, 0);

        kf0 = nk0; kf1 = nk1; vf0 = nv0; vf1 = nv1;
    }

    // atomic merge into att2 (hd, m, c) and sums (hd, m)
    float* abase = att2 + (size_t)(hd * HW + m0 + msub * 32) * 32 + lm;
#pragma unroll
    for (int r = 0; r < 16; ++r) {
        int mr = (r & 3) + 8 * (r >> 2) + 4 * h;
        atomicAdd(abase + (size_t)mr * 32, accO[r]);
    }
    float st = ssum + __shfl_xor(ssum, 32);
    if (h == 0) atomicAdd(&sums[hd * HW + mg], st);
}

// -------- normalize att2 + output 1x1 conv ---------------------------------------
__global__ __launch_bounds__(128) void combine_out_kernel(
    const float* __restrict__ att2, const float* __restrict__ sums,
    const float* __restrict__ owT, const float* __restrict__ ob, float* __restrict__ out) {
    int m0 = blockIdx.x * 8;           // 392 blocks
    int tid = threadIdx.x;             // (hd, c)
    int hd = tid >> 5, c = tid & 31;

    __shared__ float at[128 * 9];
    __shared__ float inv_s[4][8];

    if (tid < 32) {
        int hh = tid >> 3, j = tid & 7;
        inv_s[hh][j] = 1.f / sums[hh * HW + m0 + j];
    }
    __syncthreads();

#pragma unroll
    for (int j = 0; j < 8; j++)
        at[tid * 9 + j] = att2[(size_t)(hd * HW + m0 + j) * 32 + c] * inv_s[hd][j];
    __syncthreads();

    float acc[8];
#pragma unroll
    for (int j = 0; j < 8; j++) acc[j] = 0.f;
    for (int cc = 0; cc < 128; cc++) {
        float w = owT[cc * 128 + tid];
        const float* arow = at + cc * 9;
#pragma unroll
        for (int j = 0; j < 8; j++) acc[j] += w * arow[j];
    }
    float b = ob[tid];
#pragma unroll
    for (int j = 0; j < 8; j++) out[tid * HW + m0 + j] = acc[j] + b;
}

extern "C" void kernel_launch(void* const* d_in, const int* in_sizes, int n_in,
                              void* d_out, int out_size, void* d_ws, size_t ws_size,
                              hipStream_t stream) {
    const float* x     = (const float*)d_in[0];
    const float* query = (const float*)d_in[1];
    const float* dww   = (const float*)d_in[2];
    const float* dwb   = (const float*)d_in[3];
    const float* lnw   = (const float*)d_in[4];
    const float* lnb   = (const float*)d_in[5];
    const float* pww   = (const float*)d_in[6];
    const float* kw    = (const float*)d_in[7];
    const float* kb    = (const float*)d_in[8];
    const float* vw    = (const float*)d_in[9];
    const float* vb    = (const float*)d_in[10];
    const float* ow    = (const float*)d_in[11];
    const float* ob    = (const float*)d_in[12];
    const float* rpe   = (const float*)d_in[13];
    float* out = (float*)d_out;
    float* ws  = (float*)d_ws;

    prep_all_kernel<<<dim3(405, 7), 256, 0, stream>>>(
        kw, vw, ow, rpe, x, query,
        ws + OFF_KWT, ws + OFF_VWT, ws + OFF_OWT, (float2*)(ws + OFF_TP2),
        ws + OFF_XT, ws + OFF_QT, (ushortT*)(ws + OFF_QBF), ws + OFF_ATT2);
    sample_kv_kernel<<<392, 128, 0, stream>>>(
        ws + OFF_XT, ws + OFF_QT, dww, dwb, lnw, lnb, pww,
        ws + OFF_KWT, ws + OFF_VWT, kb, vb,
        (ushortT*)(ws + OFF_KBF), (ushortT*)(ws + OFF_VBF),
        (int*)(ws + OFF_AA), (float4*)(ws + OFF_W4));
    attn_kernel<<<dim3(7, 49, NHEAD), 256, 0, stream>>>(
        (const ushortT*)(ws + OFF_QBF), (const ushortT*)(ws + OFF_KBF),
        (const ushortT*)(ws + OFF_VBF),
        (const int*)(ws + OFF_AA), (const float4*)(ws + OFF_W4),
        (const float2*)(ws + OFF_TP2), ws + OFF_ATT2, ws + OFF_SUM);
    combine_out_kernel<<<392, 128, 0, stream>>>(ws + OFF_ATT2, ws + OFF_SUM,
                                                ws + OFF_OWT, ob, out);
}